// Round 1
// baseline (8076.616 us; speedup 1.0000x reference)
//
#include <hip/hip_runtime.h>

#define NN 100000
#define NE 1600000
#define NB_N ((NN + 255) / 256)
#define NB_E ((NE + 255) / 256)

// ---------------- preprocessing: CSR build ----------------

__global__ void zero_kernel(float* deg, int* cnt, int* tmp) {
    int i = blockIdx.x * 256 + threadIdx.x;
    if (i < NN) { deg[i] = 0.f; cnt[i] = 0; tmp[i] = 0; }
}

__global__ void edge_pass1(const int* __restrict__ ei, const float* __restrict__ ew,
                           float* __restrict__ deg, int* __restrict__ cnt) {
    int e = blockIdx.x * 256 + threadIdx.x;
    if (e < NE) {
        int col = ei[NE + e];
        atomicAdd(&deg[col], ew[e]);
        atomicAdd(&cnt[col], 1);
    }
}

__global__ void dis_kernel(const float* __restrict__ deg, float* __restrict__ dis) {
    int i = blockIdx.x * 256 + threadIdx.x;
    if (i < NN) {
        float d = deg[i];
        dis[i] = d > 0.f ? (float)(1.0 / sqrt((double)d)) : 0.f;
    }
}

__global__ void scan_block(const int* __restrict__ cnt, int* __restrict__ colptr,
                           int* __restrict__ bsum) {
    __shared__ int s[256];
    int t = threadIdx.x;
    int i = blockIdx.x * 256 + t;
    int v = (i < NN) ? cnt[i] : 0;
    s[t] = v;
    __syncthreads();
    for (int off = 1; off < 256; off <<= 1) {
        int x = (t >= off) ? s[t - off] : 0;
        __syncthreads();
        s[t] += x;
        __syncthreads();
    }
    if (i < NN) colptr[i] = s[t] - v;   // block-local exclusive
    if (t == 255) bsum[blockIdx.x] = s[255];
}

__global__ void scan_top(int* __restrict__ bsum, int nb) {
    __shared__ int s[512];
    int t = threadIdx.x;
    int v = (t < nb) ? bsum[t] : 0;
    s[t] = v;
    __syncthreads();
    for (int off = 1; off < 512; off <<= 1) {
        int x = (t >= off) ? s[t - off] : 0;
        __syncthreads();
        s[t] += x;
        __syncthreads();
    }
    if (t < nb) bsum[t] = s[t] - v;     // exclusive block offsets
}

__global__ void scan_add(int* __restrict__ colptr, const int* __restrict__ bsum) {
    int i = blockIdx.x * 256 + threadIdx.x;
    if (i < NN) colptr[i] += bsum[blockIdx.x];
    if (i == 0) colptr[NN] = NE;
}

__global__ void scatter_kernel(const int* __restrict__ ei, const float* __restrict__ ew,
                               const float* __restrict__ dis, const int* __restrict__ colptr,
                               int* __restrict__ tmp, int2* __restrict__ pairs) {
    int e = blockIdx.x * 256 + threadIdx.x;
    if (e < NE) {
        int r = ei[e], col = ei[NE + e];
        int p = colptr[col] + atomicAdd(&tmp[col], 1);
        float nm = dis[r] * ew[e] * dis[col];
        pairs[p] = make_int2(r, __float_as_int(nm));
    }
}

__global__ void build_x(const float* __restrict__ c, const int* __restrict__ ip,
                        float* __restrict__ X) {
    int n = blockIdx.x * 256 + threadIdx.x;
    if (n < NN) {
        int i0 = ip[0];
        float4 v;
        v.x = (n == i0) ? 1.f : 0.f;
        v.y = c[n];
        v.z = 0.f; v.w = 0.f;
        reinterpret_cast<float4*>(X)[n] = v;
    }
}

// ---------------- per-layer kernels ----------------

template <int FIN, int FINP, int FOUT, int ACCP>
__launch_bounds__(256)
__global__ void init_acc(const float* __restrict__ X, const float* __restrict__ W0,
                         const float* __restrict__ b, float* __restrict__ acc) {
    __shared__ float sW[FIN * FOUT];
    __shared__ float sb[FOUT];
    int t = threadIdx.x;
    for (int q = t; q < FIN * FOUT; q += 256) sW[q] = W0[q];
    if (t < FOUT) sb[t] = b[t];
    __syncthreads();
    int n = blockIdx.x * 256 + t;
    if (n >= NN) return;
    float x[FIN];
#pragma unroll
    for (int f = 0; f < FIN; f++) x[f] = X[(size_t)n * FINP + f];
#pragma unroll
    for (int j = 0; j < FOUT; j++) {
        float a = sb[j];
#pragma unroll
        for (int f = 0; f < FIN; f++) a = fmaf(x[f], sW[f * FOUT + j], a);
        acc[(size_t)n * ACCP + j] = a;
    }
}

template <int FIN, int FINP, int FOUT, int ACCP>
__launch_bounds__(256)
__global__ void step_kernel(const int2* __restrict__ pairs, const int* __restrict__ colptr,
                            const float* __restrict__ hin, float* __restrict__ hout,
                            float* __restrict__ acc, const float* __restrict__ Wk) {
    __shared__ float sW[FIN * FOUT];
    int t = threadIdx.x;
    for (int q = t; q < FIN * FOUT; q += 256) sW[q] = Wk[q];
    __syncthreads();
    int n = blockIdx.x * 256 + t;
    if (n >= NN) return;

    float h[FINP];
#pragma unroll
    for (int f = 0; f < FINP; f++) h[f] = 0.f;

    int e0 = colptr[n], e1 = colptr[n + 1];
    for (int e = e0; e < e1; e++) {
        int2 p = pairs[e];
        float w = __int_as_float(p.y);
        const float4* r = reinterpret_cast<const float4*>(hin + (size_t)p.x * FINP);
#pragma unroll
        for (int q = 0; q < FINP / 4; q++) {
            float4 v = r[q];
            h[4 * q + 0] = fmaf(w, v.x, h[4 * q + 0]);
            h[4 * q + 1] = fmaf(w, v.y, h[4 * q + 1]);
            h[4 * q + 2] = fmaf(w, v.z, h[4 * q + 2]);
            h[4 * q + 3] = fmaf(w, v.w, h[4 * q + 3]);
        }
    }

    float4* orow = reinterpret_cast<float4*>(hout + (size_t)n * FINP);
#pragma unroll
    for (int q = 0; q < FINP / 4; q++) {
        float4 v;
        v.x = h[4 * q + 0]; v.y = h[4 * q + 1];
        v.z = h[4 * q + 2]; v.w = h[4 * q + 3];
        orow[q] = v;
    }

    float a[FOUT];
#pragma unroll
    for (int j = 0; j < FOUT; j++) a[j] = acc[(size_t)n * ACCP + j];
#pragma unroll
    for (int f = 0; f < FIN; f++) {
        float hf = h[f];
#pragma unroll
        for (int j = 0; j < FOUT; j++) a[j] = fmaf(hf, sW[f * FOUT + j], a[j]);
    }
#pragma unroll
    for (int j = 0; j < FOUT; j++) acc[(size_t)n * ACCP + j] = a[j];
}

__global__ void relu_kernel(const float* __restrict__ acc, int accp, int fout,
                            float* __restrict__ X, int xs) {
    int n = blockIdx.x * 256 + threadIdx.x;
    if (n < NN) {
        for (int j = 0; j < xs; j++) {
            float v = (j < fout) ? fmaxf(acc[(size_t)n * accp + j], 0.f) : 0.f;
            X[(size_t)n * xs + j] = v;
        }
    }
}

// ---------------- host driver ----------------

extern "C" void kernel_launch(void* const* d_in, const int* in_sizes, int n_in,
                              void* d_out, int out_size, void* d_ws, size_t ws_size,
                              hipStream_t stream) {
    const int*   ei = (const int*)d_in[0];
    const float* ew = (const float*)d_in[1];
    const float* c  = (const float*)d_in[2];
    const int*   ip = (const int*)d_in[3];
    const float* W1 = (const float*)d_in[4];  const float* b1 = (const float*)d_in[5];
    const float* W2 = (const float*)d_in[6];  const float* b2 = (const float*)d_in[7];
    const float* W3 = (const float*)d_in[8];  const float* b3 = (const float*)d_in[9];
    const float* W4 = (const float*)d_in[10]; const float* b4 = (const float*)d_in[11];
    float* out = (float*)d_out;

    char* ws = (char*)d_ws;
    size_t off = 0;
    auto alloc = [&](size_t bytes) -> void* {
        void* p = ws + off;
        off = (off + bytes + 255) & ~(size_t)255;
        return p;
    };
    int2*  pairs  = (int2*)alloc((size_t)NE * 8);
    int*   colptr = (int*)alloc((size_t)(NN + 1) * 4);
    int*   cnt    = (int*)alloc((size_t)NN * 4);
    int*   tmp    = (int*)alloc((size_t)NN * 4);
    float* deg    = (float*)alloc((size_t)NN * 4);
    float* dis    = (float*)alloc((size_t)NN * 4);
    int*   bsum   = (int*)alloc(512 * 4);
    float* A      = (float*)alloc((size_t)NN * 32 * 4);
    float* B      = (float*)alloc((size_t)NN * 32 * 4);
    float* ACC    = (float*)alloc((size_t)NN * 32 * 4);

    zero_kernel<<<NB_N, 256, 0, stream>>>(deg, cnt, tmp);
    edge_pass1<<<NB_E, 256, 0, stream>>>(ei, ew, deg, cnt);
    dis_kernel<<<NB_N, 256, 0, stream>>>(deg, dis);
    scan_block<<<NB_N, 256, 0, stream>>>(cnt, colptr, bsum);
    scan_top<<<1, 512, 0, stream>>>(bsum, NB_N);
    scan_add<<<NB_N, 256, 0, stream>>>(colptr, bsum);
    scatter_kernel<<<NB_E, 256, 0, stream>>>(ei, ew, dis, colptr, tmp, pairs);
    build_x<<<NB_N, 256, 0, stream>>>(c, ip, A);

    // layer 1: 2 -> 15   (finp=4, accp=16)
    init_acc<2, 4, 15, 16><<<NB_N, 256, 0, stream>>>(A, W1, b1, ACC);
    {
        const float* hin = A; float* hout = B;
        for (int k = 1; k <= 50; k++) {
            step_kernel<2, 4, 15, 16><<<NB_N, 256, 0, stream>>>(
                pairs, colptr, hin, hout, ACC, W1 + (size_t)k * 2 * 15);
            const float* t2 = hin; hin = hout; hout = (float*)t2;
        }
    }
    relu_kernel<<<NB_N, 256, 0, stream>>>(ACC, 16, 15, A, 16);

    // layer 2: 15 -> 30  (finp=16, accp=32)
    init_acc<15, 16, 30, 32><<<NB_N, 256, 0, stream>>>(A, W2, b2, ACC);
    {
        const float* hin = A; float* hout = B;
        for (int k = 1; k <= 50; k++) {
            step_kernel<15, 16, 30, 32><<<NB_N, 256, 0, stream>>>(
                pairs, colptr, hin, hout, ACC, W2 + (size_t)k * 15 * 30);
            const float* t2 = hin; hin = hout; hout = (float*)t2;
        }
    }
    relu_kernel<<<NB_N, 256, 0, stream>>>(ACC, 32, 30, A, 32);

    // layer 3: 30 -> 15  (finp=32, accp=16)
    init_acc<30, 32, 15, 16><<<NB_N, 256, 0, stream>>>(A, W3, b3, ACC);
    {
        const float* hin = A; float* hout = B;
        for (int k = 1; k <= 50; k++) {
            step_kernel<30, 32, 15, 16><<<NB_N, 256, 0, stream>>>(
                pairs, colptr, hin, hout, ACC, W3 + (size_t)k * 30 * 15);
            const float* t2 = hin; hin = hout; hout = (float*)t2;
        }
    }
    relu_kernel<<<NB_N, 256, 0, stream>>>(ACC, 16, 15, A, 16);

    // layer 4: 15 -> 1   (finp=16, accp=1)
    init_acc<15, 16, 1, 1><<<NB_N, 256, 0, stream>>>(A, W4, b4, ACC);
    {
        const float* hin = A; float* hout = B;
        for (int k = 1; k <= 50; k++) {
            step_kernel<15, 16, 1, 1><<<NB_N, 256, 0, stream>>>(
                pairs, colptr, hin, hout, ACC, W4 + (size_t)k * 15 * 1);
            const float* t2 = hin; hin = hout; hout = (float*)t2;
        }
    }
    relu_kernel<<<NB_N, 256, 0, stream>>>(ACC, 1, 1, out, 1);
}

// Round 2
// 7321.426 us; speedup vs baseline: 1.1031x; 1.1031x over previous
//
#include <hip/hip_runtime.h>

#define NN 100000
#define NE 1600000
#define NB_N ((NN + 255) / 256)
#define NB_E ((NE + 255) / 256)

// ---------------- preprocessing: CSR build ----------------

__global__ void zero_kernel(int* __restrict__ cnt) {
    int i = blockIdx.x * 256 + threadIdx.x;
    if (i < NN) cnt[i] = 0;
}

// One atomic per edge; remember the rank so scatter needs none.
__global__ void edge_pass1(const int* __restrict__ ei, int* __restrict__ cnt,
                           int* __restrict__ rank) {
    int e = blockIdx.x * 256 + threadIdx.x;
    if (e < NE) {
        int col = ei[NE + e];
        rank[e] = atomicAdd(&cnt[col], 1);
    }
}

__global__ void scan_block(const int* __restrict__ cnt, int* __restrict__ colptr,
                           int* __restrict__ bsum) {
    __shared__ int s[256];
    int t = threadIdx.x;
    int i = blockIdx.x * 256 + t;
    int v = (i < NN) ? cnt[i] : 0;
    s[t] = v;
    __syncthreads();
    for (int off = 1; off < 256; off <<= 1) {
        int x = (t >= off) ? s[t - off] : 0;
        __syncthreads();
        s[t] += x;
        __syncthreads();
    }
    if (i < NN) colptr[i] = s[t] - v;   // block-local exclusive
    if (t == 255) bsum[blockIdx.x] = s[255];
}

__global__ void scan_top(int* __restrict__ bsum, int nb) {
    __shared__ int s[512];
    int t = threadIdx.x;
    int v = (t < nb) ? bsum[t] : 0;
    s[t] = v;
    __syncthreads();
    for (int off = 1; off < 512; off <<= 1) {
        int x = (t >= off) ? s[t - off] : 0;
        __syncthreads();
        s[t] += x;
        __syncthreads();
    }
    if (t < nb) bsum[t] = s[t] - v;     // exclusive block offsets
}

__global__ void scan_add(int* __restrict__ colptr, const int* __restrict__ bsum) {
    int i = blockIdx.x * 256 + threadIdx.x;
    if (i < NN) colptr[i] += bsum[blockIdx.x];
    if (i == 0) colptr[NN] = NE;
}

// Atomic-free scatter: store (src, raw weight)
__global__ void scatter_kernel(const int* __restrict__ ei, const float* __restrict__ ew,
                               const int* __restrict__ colptr, const int* __restrict__ rank,
                               int2* __restrict__ pairs) {
    int e = blockIdx.x * 256 + threadIdx.x;
    if (e < NE) {
        int r = ei[e], col = ei[NE + e];
        pairs[colptr[col] + rank[e]] = make_int2(r, __float_as_int(ew[e]));
    }
}

// Atomic-free degree: sum raw weights along each node's CSR range
__global__ void deg_dis_kernel(const int2* __restrict__ pairs, const int* __restrict__ colptr,
                               float* __restrict__ dis) {
    int n = blockIdx.x * 256 + threadIdx.x;
    if (n < NN) {
        int e0 = colptr[n], e1 = colptr[n + 1];
        float d = 0.f;
        for (int e = e0; e < e1; e++) d += __int_as_float(pairs[e].y);
        dis[n] = d > 0.f ? (float)(1.0 / sqrt((double)d)) : 0.f;
    }
}

// pairs[p].w = dis[src] * w * dis[col]   (dis is 400KB -> L2-resident gathers)
__global__ void rescale_kernel(int2* __restrict__ pairs, const int* __restrict__ colptr,
                               const float* __restrict__ dis) {
    int n = blockIdx.x * 256 + threadIdx.x;
    if (n < NN) {
        float dn = dis[n];
        int e0 = colptr[n], e1 = colptr[n + 1];
        for (int e = e0; e < e1; e++) {
            int2 p = pairs[e];
            float nm = dis[p.x] * __int_as_float(p.y) * dn;
            pairs[e] = make_int2(p.x, __float_as_int(nm));
        }
    }
}

__global__ void build_x(const float* __restrict__ c, const int* __restrict__ ip,
                        float* __restrict__ X) {
    int n = blockIdx.x * 256 + threadIdx.x;
    if (n < NN) {
        int i0 = ip[0];
        float4 v;
        v.x = (n == i0) ? 1.f : 0.f;
        v.y = c[n];
        v.z = 0.f; v.w = 0.f;
        reinterpret_cast<float4*>(X)[n] = v;
    }
}

// ---------------- per-layer kernels ----------------

template <int FIN, int FINP, int FOUT, int ACCP>
__launch_bounds__(256)
__global__ void init_acc(const float* __restrict__ X, const float* __restrict__ W0,
                         const float* __restrict__ b, float* __restrict__ acc) {
    __shared__ float sW[FIN * FOUT];
    __shared__ float sb[FOUT];
    int t = threadIdx.x;
    for (int q = t; q < FIN * FOUT; q += 256) sW[q] = W0[q];
    if (t < FOUT) sb[t] = b[t];
    __syncthreads();
    int n = blockIdx.x * 256 + t;
    if (n >= NN) return;
    float x[FIN];
#pragma unroll
    for (int f = 0; f < FIN; f++) x[f] = X[(size_t)n * FINP + f];
#pragma unroll
    for (int j = 0; j < FOUT; j++) {
        float a = sb[j];
#pragma unroll
        for (int f = 0; f < FIN; f++) a = fmaf(x[f], sW[f * FOUT + j], a);
        acc[(size_t)n * ACCP + j] = a;
    }
}

// Lane-group SpMM step: LG lanes per node, each lane holds VPL floats of the row.
// Per edge: one broadcast pair load + one coalesced LG*VPL*4-byte row load.
template <int FIN, int FINP, int FOUT, int ACCP, int LG, int VPL>
__launch_bounds__(256)
__global__ void step_kernel(const int2* __restrict__ pairs, const int* __restrict__ colptr,
                            const float* __restrict__ hin, float* __restrict__ hout,
                            float* __restrict__ acc, const float* __restrict__ Wk) {
    constexpr int GPB = 256 / LG;   // groups (nodes) per block
    __shared__ float sW[FIN * FOUT];
    __shared__ float sh[GPB][FINP];
    int t = threadIdx.x;
    for (int q = t; q < FIN * FOUT; q += 256) sW[q] = Wk[q];
    __syncthreads();

    int g = t / LG, lane = t % LG;
    int n = blockIdx.x * GPB + g;
    if (n >= NN) return;

    float h[VPL];
#pragma unroll
    for (int v = 0; v < VPL; v++) h[v] = 0.f;

    int e0 = colptr[n], e1 = colptr[n + 1];
    for (int e = e0; e < e1; e++) {
        int2 p = pairs[e];
        float w = __int_as_float(p.y);
        const float* r = hin + (size_t)p.x * FINP + lane * VPL;
        if constexpr (VPL == 1) {
            h[0] = fmaf(w, r[0], h[0]);
        } else if constexpr (VPL == 2) {
            float2 v = *reinterpret_cast<const float2*>(r);
            h[0] = fmaf(w, v.x, h[0]);
            h[1] = fmaf(w, v.y, h[1]);
        } else {
            float4 v = *reinterpret_cast<const float4*>(r);
            h[0] = fmaf(w, v.x, h[0]);
            h[1] = fmaf(w, v.y, h[1]);
            h[2] = fmaf(w, v.z, h[2]);
            h[3] = fmaf(w, v.w, h[3]);
        }
    }

    // write h row (coalesced across the group)
    float* o = hout + (size_t)n * FINP + lane * VPL;
    if constexpr (VPL == 1) {
        o[0] = h[0];
    } else if constexpr (VPL == 2) {
        float2 v; v.x = h[0]; v.y = h[1];
        *reinterpret_cast<float2*>(o) = v;
    } else {
        float4 v; v.x = h[0]; v.y = h[1]; v.z = h[2]; v.w = h[3];
        *reinterpret_cast<float4*>(o) = v;
    }

    // stash h into LDS for the mini-GEMM; group lanes are within one wave,
    // same-wave ds ordering makes this safe without a barrier.
#pragma unroll
    for (int v = 0; v < VPL; v++) sh[g][lane * VPL + v] = h[v];

    // acc[j] += sum_f h[f] * W[f,j]; lanes own output columns j, j+LG, ...
    for (int j = lane; j < FOUT; j += LG) {
        float a = acc[(size_t)n * ACCP + j];
#pragma unroll
        for (int f = 0; f < FIN; f++) a = fmaf(sh[g][f], sW[f * FOUT + j], a);
        acc[(size_t)n * ACCP + j] = a;
    }
}

__global__ void relu_kernel(const float* __restrict__ acc, int accp, int fout,
                            float* __restrict__ X, int xs) {
    int n = blockIdx.x * 256 + threadIdx.x;
    if (n < NN) {
        for (int j = 0; j < xs; j++) {
            float v = (j < fout) ? fmaxf(acc[(size_t)n * accp + j], 0.f) : 0.f;
            X[(size_t)n * xs + j] = v;
        }
    }
}

// ---------------- host driver ----------------

extern "C" void kernel_launch(void* const* d_in, const int* in_sizes, int n_in,
                              void* d_out, int out_size, void* d_ws, size_t ws_size,
                              hipStream_t stream) {
    const int*   ei = (const int*)d_in[0];
    const float* ew = (const float*)d_in[1];
    const float* c  = (const float*)d_in[2];
    const int*   ip = (const int*)d_in[3];
    const float* W1 = (const float*)d_in[4];  const float* b1 = (const float*)d_in[5];
    const float* W2 = (const float*)d_in[6];  const float* b2 = (const float*)d_in[7];
    const float* W3 = (const float*)d_in[8];  const float* b3 = (const float*)d_in[9];
    const float* W4 = (const float*)d_in[10]; const float* b4 = (const float*)d_in[11];
    float* out = (float*)d_out;

    char* ws = (char*)d_ws;
    size_t off = 0;
    auto alloc = [&](size_t bytes) -> void* {
        void* p = ws + off;
        off = (off + bytes + 255) & ~(size_t)255;
        return p;
    };
    int2*  pairs  = (int2*)alloc((size_t)NE * 8);
    int*   colptr = (int*)alloc((size_t)(NN + 1) * 4);
    int*   cnt    = (int*)alloc((size_t)NN * 4);
    int*   rank   = (int*)alloc((size_t)NE * 4);
    float* dis    = (float*)alloc((size_t)NN * 4);
    int*   bsum   = (int*)alloc(512 * 4);
    float* A      = (float*)alloc((size_t)NN * 32 * 4);
    float* B      = (float*)alloc((size_t)NN * 32 * 4);
    float* ACC    = (float*)alloc((size_t)NN * 32 * 4);

    zero_kernel<<<NB_N, 256, 0, stream>>>(cnt);
    edge_pass1<<<NB_E, 256, 0, stream>>>(ei, cnt, rank);
    scan_block<<<NB_N, 256, 0, stream>>>(cnt, colptr, bsum);
    scan_top<<<1, 512, 0, stream>>>(bsum, NB_N);
    scan_add<<<NB_N, 256, 0, stream>>>(colptr, bsum);
    scatter_kernel<<<NB_E, 256, 0, stream>>>(ei, ew, colptr, rank, pairs);
    deg_dis_kernel<<<NB_N, 256, 0, stream>>>(pairs, colptr, dis);
    rescale_kernel<<<NB_N, 256, 0, stream>>>(pairs, colptr, dis);
    build_x<<<NB_N, 256, 0, stream>>>(c, ip, A);

    // layer 1: 2 -> 15   (finp=4, accp=16, LG=4, VPL=1)
    init_acc<2, 4, 15, 16><<<NB_N, 256, 0, stream>>>(A, W1, b1, ACC);
    {
        const float* hin = A; float* hout = B;
        const int GPB = 64, NB = (NN + GPB - 1) / GPB;
        for (int k = 1; k <= 50; k++) {
            step_kernel<2, 4, 15, 16, 4, 1><<<NB, 256, 0, stream>>>(
                pairs, colptr, hin, hout, ACC, W1 + (size_t)k * 2 * 15);
            const float* t2 = hin; hin = hout; hout = (float*)t2;
        }
    }
    relu_kernel<<<NB_N, 256, 0, stream>>>(ACC, 16, 15, A, 16);

    // layer 2: 15 -> 30  (finp=16, accp=32, LG=8, VPL=2)
    init_acc<15, 16, 30, 32><<<NB_N, 256, 0, stream>>>(A, W2, b2, ACC);
    {
        const float* hin = A; float* hout = B;
        const int GPB = 32, NB = (NN + GPB - 1) / GPB;
        for (int k = 1; k <= 50; k++) {
            step_kernel<15, 16, 30, 32, 8, 2><<<NB, 256, 0, stream>>>(
                pairs, colptr, hin, hout, ACC, W2 + (size_t)k * 15 * 30);
            const float* t2 = hin; hin = hout; hout = (float*)t2;
        }
    }
    relu_kernel<<<NB_N, 256, 0, stream>>>(ACC, 32, 30, A, 32);

    // layer 3: 30 -> 15  (finp=32, accp=16, LG=8, VPL=4)
    init_acc<30, 32, 15, 16><<<NB_N, 256, 0, stream>>>(A, W3, b3, ACC);
    {
        const float* hin = A; float* hout = B;
        const int GPB = 32, NB = (NN + GPB - 1) / GPB;
        for (int k = 1; k <= 50; k++) {
            step_kernel<30, 32, 15, 16, 8, 4><<<NB, 256, 0, stream>>>(
                pairs, colptr, hin, hout, ACC, W3 + (size_t)k * 30 * 15);
            const float* t2 = hin; hin = hout; hout = (float*)t2;
        }
    }
    relu_kernel<<<NB_N, 256, 0, stream>>>(ACC, 16, 15, A, 16);

    // layer 4: 15 -> 1   (finp=16, accp=1, LG=8, VPL=2)
    init_acc<15, 16, 1, 1><<<NB_N, 256, 0, stream>>>(A, W4, b4, ACC);
    {
        const float* hin = A; float* hout = B;
        const int GPB = 32, NB = (NN + GPB - 1) / GPB;
        for (int k = 1; k <= 50; k++) {
            step_kernel<15, 16, 1, 1, 8, 2><<<NB, 256, 0, stream>>>(
                pairs, colptr, hin, hout, ACC, W4 + (size_t)k * 15 * 1);
            const float* t2 = hin; hin = hout; hout = (float*)t2;
        }
    }
    relu_kernel<<<NB_N, 256, 0, stream>>>(ACC, 1, 1, out, 1);
}